// Round 1
// baseline (317.915 us; speedup 1.0000x reference)
//
#include <hip/hip_runtime.h>

#define S_LEN 2048
#define D_MODEL 1024
#define NH 16
#define DH 64
#define M_TOK 4096  // B*S

typedef __attribute__((ext_vector_type(8))) short bf16x8;
typedef __attribute__((ext_vector_type(4))) float f32x4;

__device__ __forceinline__ unsigned short f2bf(float f) {
  unsigned u = __float_as_uint(f);
  u += 0x7FFF + ((u >> 16) & 1);  // RNE
  return (unsigned short)(u >> 16);
}

// ---------------- kernel 1: cast weights to bf16, zero energy ----------------
__global__ __launch_bounds__(256) void prep_kernel(
    const float* __restrict__ Wq, const float* __restrict__ Wk,
    const float* __restrict__ Wv, const float* __restrict__ Wo,
    unsigned short* __restrict__ wbf, float* __restrict__ energy) {
  if (blockIdx.x == 0 && threadIdx.x == 0) *energy = 0.f;
  int idx = (blockIdx.x * 256 + threadIdx.x) * 4;
  int wsel = idx >> 20;  // 1048576 elements per weight
  const float* s = (wsel == 0) ? Wq : (wsel == 1) ? Wk : (wsel == 2) ? Wv : Wo;
  int off = idx & 1048575;
  float4 v = *(const float4*)(s + off);
  ushort4 p;
  p.x = f2bf(v.x); p.y = f2bf(v.y); p.z = f2bf(v.z); p.w = f2bf(v.w);
  *(ushort4*)(wbf + idx) = p;
}

// ---------------- kernel 2: LayerNorm + phase ----------------
__device__ __forceinline__ float block_sum(float v, float* sm) {
#pragma unroll
  for (int o = 32; o > 0; o >>= 1) v += __shfl_xor(v, o, 64);
  int w = threadIdx.x >> 6;
  __syncthreads();
  if ((threadIdx.x & 63) == 0) sm[w] = v;
  __syncthreads();
  return sm[0] + sm[1] + sm[2] + sm[3];
}

__global__ __launch_bounds__(256) void ln_phase_kernel(
    const float* __restrict__ x, const float* __restrict__ Wp,
    const float* __restrict__ gamma, const float* __restrict__ beta,
    unsigned short* __restrict__ xn, float* __restrict__ cosP,
    float* __restrict__ sinP) {
  __shared__ float sm[4];
  int row = blockIdx.x;
  int tid = threadIdx.x;
  float4 v = ((const float4*)(x + (size_t)row * D_MODEL))[tid];
  float mu = block_sum(v.x + v.y + v.z + v.w, sm) * (1.0f / D_MODEL);
  float d0 = v.x - mu, d1 = v.y - mu, d2 = v.z - mu, d3 = v.w - mu;
  float var = block_sum(d0 * d0 + d1 * d1 + d2 * d2 + d3 * d3, sm) * (1.0f / D_MODEL);
  float rinv = rsqrtf(var + 1e-5f);
  float4 g = ((const float4*)gamma)[tid];
  float4 be = ((const float4*)beta)[tid];
  float n0 = d0 * rinv * g.x + be.x;
  float n1 = d1 * rinv * g.y + be.y;
  float n2 = d2 * rinv * g.z + be.z;
  float n3 = d3 * rinv * g.w + be.w;
  ushort4 p;
  p.x = f2bf(n0); p.y = f2bf(n1); p.z = f2bf(n2); p.w = f2bf(n3);
  ((ushort4*)(xn + (size_t)row * D_MODEL))[tid] = p;
  float4 wp = ((const float4*)Wp)[tid];
  float ph = block_sum(n0 * wp.x + n1 * wp.y + n2 * wp.z + n3 * wp.w, sm);
  if (tid == 0) {
    cosP[row] = cosf(ph);
    sinP[row] = sinf(ph);
  }
}

// ---------------- kernel 3: QKV GEMM (NT, bf16 MFMA) ----------------
// A = xn (M x K), B = W (N x K, torch Linear => y = x W^T). z picks Q/K/V.
__global__ __launch_bounds__(256) void qkv_gemm_kernel(
    const unsigned short* __restrict__ xn, const unsigned short* __restrict__ wbf,
    unsigned short* __restrict__ q, unsigned short* __restrict__ k,
    unsigned short* __restrict__ vT) {
  __shared__ __align__(16) unsigned short As[128 * 32];
  __shared__ __align__(16) unsigned short Bs[128 * 32];
  int z = blockIdx.z;
  const unsigned short* Bm = wbf + (size_t)z * (D_MODEL * D_MODEL);
  int tid = threadIdx.x;
  int wave = tid >> 6, lane = tid & 63, quad = lane >> 4, l15 = lane & 15;
  int wm = (wave & 1) * 64, wn = (wave >> 1) * 64;
  int m0 = blockIdx.y * 128, n0 = blockIdx.x * 128;
  f32x4 acc[4][4];
#pragma unroll
  for (int r = 0; r < 4; ++r)
#pragma unroll
    for (int c = 0; c < 4; ++c) acc[r][c] = (f32x4){0.f, 0.f, 0.f, 0.f};

  for (int k0 = 0; k0 < D_MODEL; k0 += 32) {
    __syncthreads();
#pragma unroll
    for (int t = 0; t < 2; ++t) {
      int c = t * 256 + tid;
      int r = c >> 2, cc = (c & 3) * 8;
      *(int4*)&As[r * 32 + cc] = *(const int4*)&xn[(size_t)(m0 + r) * D_MODEL + k0 + cc];
      *(int4*)&Bs[r * 32 + cc] = *(const int4*)&Bm[(size_t)(n0 + r) * D_MODEL + k0 + cc];
    }
    __syncthreads();
    bf16x8 af[4], bfr[4];
#pragma unroll
    for (int r = 0; r < 4; ++r) af[r] = *(const bf16x8*)&As[(wm + r * 16 + l15) * 32 + quad * 8];
#pragma unroll
    for (int c = 0; c < 4; ++c) bfr[c] = *(const bf16x8*)&Bs[(wn + c * 16 + l15) * 32 + quad * 8];
#pragma unroll
    for (int r = 0; r < 4; ++r)
#pragma unroll
      for (int c = 0; c < 4; ++c)
        acc[r][c] = __builtin_amdgcn_mfma_f32_16x16x32_bf16(af[r], bfr[c], acc[r][c], 0, 0, 0);
  }
  float scl = (z == 0) ? 0.125f : 1.0f;  // fold 1/sqrt(dh) into Q
#pragma unroll
  for (int r = 0; r < 4; ++r) {
#pragma unroll
    for (int c = 0; c < 4; ++c) {
      int ecol = n0 + wn + c * 16 + l15;
      int hh = ecol >> 6, d = ecol & 63;
#pragma unroll
      for (int rr = 0; rr < 4; ++rr) {
        int tok = m0 + wm + r * 16 + quad * 4 + rr;
        int bb = tok >> 11, ss = tok & (S_LEN - 1);
        unsigned short val = f2bf(acc[r][c][rr] * scl);
        int bh = bb * NH + hh;
        if (z == 0)
          q[((size_t)bh * S_LEN + ss) * DH + d] = val;
        else if (z == 1)
          k[((size_t)bh * S_LEN + ss) * DH + d] = val;
        else
          vT[((size_t)bh * DH + d) * S_LEN + ss] = val;  // V transposed
      }
    }
  }
}

// ---------------- kernel 4: flash attention with resonance ----------------
__global__ __launch_bounds__(256) void attn_kernel(
    const unsigned short* __restrict__ q, const unsigned short* __restrict__ kk,
    const unsigned short* __restrict__ vT, const float* __restrict__ cosP,
    const float* __restrict__ sinP, const float* __restrict__ carrier,
    const float* __restrict__ lamp, unsigned short* __restrict__ outw,
    float* __restrict__ energy) {
  __shared__ __align__(16) unsigned short Ks[64 * 64];
  __shared__ __align__(16) unsigned short Vs[64 * 64];  // Vs[d][j]
  __shared__ __align__(16) unsigned short Ps[4][16 * 64];
  __shared__ float er[4];
  int qt = blockIdx.x, h = blockIdx.y, b = blockIdx.z;
  int bh = b * NH + h;
  int tid = threadIdx.x, wave = tid >> 6, lane = tid & 63;
  int quad = lane >> 4, l15 = lane & 15;
  float hl = 0.5f * lamp[0];
  float ch = cosf(carrier[h]), sh = sinf(carrier[h]);
  const unsigned short* qb = q + ((size_t)bh * S_LEN + qt * 64) * DH;
  const unsigned short* kb = kk + (size_t)bh * S_LEN * DH;
  const unsigned short* vb = vT + (size_t)bh * DH * S_LEN;
  const float* cpb = cosP + b * S_LEN;
  const float* spb = sinP + b * S_LEN;

  int qrow = wave * 16 + l15;
  bf16x8 aQ0 = *(const bf16x8*)(qb + qrow * DH + quad * 8);
  bf16x8 aQ1 = *(const bf16x8*)(qb + qrow * DH + 32 + quad * 8);

  float cI[4], sI[4], m_i[4], l_i[4];
  f32x4 o[4];
#pragma unroll
  for (int r = 0; r < 4; ++r) {
    int il = qt * 64 + wave * 16 + quad * 4 + r;
    cI[r] = hl * cpb[il];
    sI[r] = hl * spb[il];
    m_i[r] = -3.0e38f;
    l_i[r] = 0.f;
    o[r] = (f32x4){0.f, 0.f, 0.f, 0.f};
  }

  for (int j0 = 0; j0 < S_LEN; j0 += 64) {
    __syncthreads();
#pragma unroll
    for (int t = 0; t < 2; ++t) {
      int c = t * 256 + tid;
      int r = c >> 3, c8 = (c & 7) * 8;
      *(int4*)&Ks[r * 64 + c8] = *(const int4*)&kb[(size_t)(j0 + r) * DH + c8];
      *(int4*)&Vs[r * 64 + c8] = *(const int4*)&vb[(size_t)r * S_LEN + j0 + c8];
    }
    __syncthreads();

    float Sc[4][4];
#pragma unroll
    for (int cg = 0; cg < 4; ++cg) {
      bf16x8 b0 = *(const bf16x8*)&Ks[(cg * 16 + l15) * 64 + quad * 8];
      bf16x8 b1 = *(const bf16x8*)&Ks[(cg * 16 + l15) * 64 + 32 + quad * 8];
      f32x4 cfr = (f32x4){0.f, 0.f, 0.f, 0.f};
      cfr = __builtin_amdgcn_mfma_f32_16x16x32_bf16(aQ0, b0, cfr, 0, 0, 0);
      cfr = __builtin_amdgcn_mfma_f32_16x16x32_bf16(aQ1, b1, cfr, 0, 0, 0);
      int j = j0 + cg * 16 + l15;
      float cj = cpb[j], sj = spb[j];
#pragma unroll
      for (int r = 0; r < 4; ++r) Sc[cg][r] = cfr[r] + cI[r] * cj + sI[r] * sj;
    }
#pragma unroll
    for (int r = 0; r < 4; ++r) {
      float mx = fmaxf(fmaxf(Sc[0][r], Sc[1][r]), fmaxf(Sc[2][r], Sc[3][r]));
      mx = fmaxf(mx, __shfl_xor(mx, 1, 64));
      mx = fmaxf(mx, __shfl_xor(mx, 2, 64));
      mx = fmaxf(mx, __shfl_xor(mx, 4, 64));
      mx = fmaxf(mx, __shfl_xor(mx, 8, 64));
      float mnew = fmaxf(m_i[r], mx);
      float ps = 0.f;
#pragma unroll
      for (int cg = 0; cg < 4; ++cg) {
        float pv = __expf(Sc[cg][r] - mnew);
        Sc[cg][r] = pv;
        ps += pv;
      }
      ps += __shfl_xor(ps, 1, 64);
      ps += __shfl_xor(ps, 2, 64);
      ps += __shfl_xor(ps, 4, 64);
      ps += __shfl_xor(ps, 8, 64);
      float alpha = __expf(m_i[r] - mnew);
      l_i[r] = l_i[r] * alpha + ps;
      m_i[r] = mnew;
#pragma unroll
      for (int dg = 0; dg < 4; ++dg) o[dg][r] *= alpha;
    }
    // P (C-layout) -> A-layout via per-wave LDS round trip
#pragma unroll
    for (int cg = 0; cg < 4; ++cg)
#pragma unroll
      for (int r = 0; r < 4; ++r)
        Ps[wave][(quad * 4 + r) * 64 + cg * 16 + l15] = f2bf(Sc[cg][r]);
#pragma unroll
    for (int hh2 = 0; hh2 < 2; ++hh2) {
      bf16x8 aP = *(const bf16x8*)&Ps[wave][l15 * 64 + hh2 * 32 + quad * 8];
#pragma unroll
      for (int dg = 0; dg < 4; ++dg) {
        bf16x8 bV = *(const bf16x8*)&Vs[(dg * 16 + l15) * 64 + hh2 * 32 + quad * 8];
        o[dg] = __builtin_amdgcn_mfma_f32_16x16x32_bf16(aP, bV, o[dg], 0, 0, 0);
      }
    }
  }
  // epilogue: normalize, gate, store, energy
  float esum = 0.f;
#pragma unroll
  for (int r = 0; r < 4; ++r) {
    int il = wave * 16 + quad * 4 + r;
    int srow = qt * 64 + il;
    float cp = cpb[srow], sp = spb[srow];
    float gate = 0.5f + 0.5f * (cp * ch + sp * sh);
    float gl = gate / l_i[r];
    int tok = b * S_LEN + srow;
#pragma unroll
    for (int dg = 0; dg < 4; ++dg) {
      float val = o[dg][r] * gl;
      esum += fabsf(val);
      outw[(size_t)tok * D_MODEL + h * DH + dg * 16 + l15] = f2bf(val);
    }
  }
#pragma unroll
  for (int off = 32; off > 0; off >>= 1) esum += __shfl_xor(esum, off, 64);
  if (lane == 0) er[wave] = esum;
  __syncthreads();
  if (tid == 0) atomicAdd(energy, er[0] + er[1] + er[2] + er[3]);
}

// ---------------- kernel 5: output projection + residual ----------------
__global__ __launch_bounds__(256) void out_gemm_kernel(
    const unsigned short* __restrict__ A, const unsigned short* __restrict__ Wo,
    const float* __restrict__ x, float* __restrict__ y) {
  __shared__ __align__(16) unsigned short As[128 * 32];
  __shared__ __align__(16) unsigned short Bs[128 * 32];
  int tid = threadIdx.x;
  int wave = tid >> 6, lane = tid & 63, quad = lane >> 4, l15 = lane & 15;
  int wm = (wave & 1) * 64, wn = (wave >> 1) * 64;
  int m0 = blockIdx.y * 128, n0 = blockIdx.x * 128;
  f32x4 acc[4][4];
#pragma unroll
  for (int r = 0; r < 4; ++r)
#pragma unroll
    for (int c = 0; c < 4; ++c) acc[r][c] = (f32x4){0.f, 0.f, 0.f, 0.f};

  for (int k0 = 0; k0 < D_MODEL; k0 += 32) {
    __syncthreads();
#pragma unroll
    for (int t = 0; t < 2; ++t) {
      int c = t * 256 + tid;
      int r = c >> 2, cc = (c & 3) * 8;
      *(int4*)&As[r * 32 + cc] = *(const int4*)&A[(size_t)(m0 + r) * D_MODEL + k0 + cc];
      *(int4*)&Bs[r * 32 + cc] = *(const int4*)&Wo[(size_t)(n0 + r) * D_MODEL + k0 + cc];
    }
    __syncthreads();
    bf16x8 af[4], bfr[4];
#pragma unroll
    for (int r = 0; r < 4; ++r) af[r] = *(const bf16x8*)&As[(wm + r * 16 + l15) * 32 + quad * 8];
#pragma unroll
    for (int c = 0; c < 4; ++c) bfr[c] = *(const bf16x8*)&Bs[(wn + c * 16 + l15) * 32 + quad * 8];
#pragma unroll
    for (int r = 0; r < 4; ++r)
#pragma unroll
      for (int c = 0; c < 4; ++c)
        acc[r][c] = __builtin_amdgcn_mfma_f32_16x16x32_bf16(af[r], bfr[c], acc[r][c], 0, 0, 0);
  }
#pragma unroll
  for (int r = 0; r < 4; ++r) {
#pragma unroll
    for (int c = 0; c < 4; ++c) {
      int dcol = n0 + wn + c * 16 + l15;
#pragma unroll
      for (int rr = 0; rr < 4; ++rr) {
        int tok = m0 + wm + r * 16 + quad * 4 + rr;
        size_t idx = (size_t)tok * D_MODEL + dcol;
        y[idx] = x[idx] + acc[r][c][rr];
      }
    }
  }
}

extern "C" void kernel_launch(void* const* d_in, const int* in_sizes, int n_in,
                              void* d_out, int out_size, void* d_ws, size_t ws_size,
                              hipStream_t stream) {
  const float* x = (const float*)d_in[0];
  const float* Wq = (const float*)d_in[1];
  const float* Wk = (const float*)d_in[2];
  const float* Wv = (const float*)d_in[3];
  const float* Wo = (const float*)d_in[4];
  const float* Wp = (const float*)d_in[5];
  const float* gamma = (const float*)d_in[6];
  const float* beta = (const float*)d_in[7];
  const float* carrier = (const float*)d_in[8];
  const float* lam = (const float*)d_in[9];

  char* ws = (char*)d_ws;
  const size_t MB = 1024 * 1024;
  unsigned short* wbf = (unsigned short*)(ws);             // 8 MB: Wq|Wk|Wv|Wo bf16
  unsigned short* xn = (unsigned short*)(ws + 8 * MB);     // 8 MB
  unsigned short* qq = (unsigned short*)(ws + 16 * MB);    // 8 MB (B,H,S,dh)
  unsigned short* kk = (unsigned short*)(ws + 24 * MB);    // 8 MB (B,H,S,dh)
  unsigned short* vT = (unsigned short*)(ws + 32 * MB);    // 8 MB (B,H,dh,S)
  unsigned short* outw = (unsigned short*)(ws + 40 * MB);  // 8 MB (tok, e)
  float* cosP = (float*)(ws + 48 * MB);                    // 16 KB
  float* sinP = (float*)(ws + 48 * MB + 16 * 1024);        // 16 KB

  float* y = (float*)d_out;
  float* energy = y + (out_size - 1);

  prep_kernel<<<4096, 256, 0, stream>>>(Wq, Wk, Wv, Wo, wbf, energy);
  ln_phase_kernel<<<M_TOK, 256, 0, stream>>>(x, Wp, gamma, beta, xn, cosP, sinP);
  qkv_gemm_kernel<<<dim3(8, 32, 3), 256, 0, stream>>>(xn, wbf, qq, kk, vT);
  attn_kernel<<<dim3(32, 16, 2), 256, 0, stream>>>(qq, kk, vT, cosP, sinP, carrier,
                                                   lam, outw, energy);
  out_gemm_kernel<<<dim3(8, 32), 256, 0, stream>>>(outw, wbf + 3 * D_MODEL * D_MODEL,
                                                   x, y);
}

// Round 2
// 302.415 us; speedup vs baseline: 1.0513x; 1.0513x over previous
//
#include <hip/hip_runtime.h>

#define S_LEN 2048
#define D_MODEL 1024
#define NH 16
#define DH 64
#define M_TOK 4096  // B*S

typedef __attribute__((ext_vector_type(8))) short bf16x8;
typedef __attribute__((ext_vector_type(4))) float f32x4;

__device__ __forceinline__ unsigned short f2bf(float f) {
  unsigned u = __float_as_uint(f);
  u += 0x7FFF + ((u >> 16) & 1);  // RNE
  return (unsigned short)(u >> 16);
}

// async 16B global->LDS (wave-uniform LDS base + lane*16 required)
__device__ __forceinline__ void gl16(const void* g, void* l) {
  __builtin_amdgcn_global_load_lds(
      (const __attribute__((address_space(1))) unsigned int*)g,
      (__attribute__((address_space(3))) unsigned int*)l, 16, 0, 0);
}

// ---------------- kernel 1: cast weights to bf16, zero energy ----------------
__global__ __launch_bounds__(256) void prep_kernel(
    const float* __restrict__ Wq, const float* __restrict__ Wk,
    const float* __restrict__ Wv, const float* __restrict__ Wo,
    unsigned short* __restrict__ wbf, float* __restrict__ energy) {
  if (blockIdx.x == 0 && threadIdx.x == 0) *energy = 0.f;
  int idx = (blockIdx.x * 256 + threadIdx.x) * 4;
  int wsel = idx >> 20;  // 1048576 elements per weight
  const float* s = (wsel == 0) ? Wq : (wsel == 1) ? Wk : (wsel == 2) ? Wv : Wo;
  int off = idx & 1048575;
  float4 v = *(const float4*)(s + off);
  ushort4 p;
  p.x = f2bf(v.x); p.y = f2bf(v.y); p.z = f2bf(v.z); p.w = f2bf(v.w);
  *(ushort4*)(wbf + idx) = p;
}

// ---------------- kernel 2: LayerNorm + phase ----------------
__device__ __forceinline__ float block_sum(float v, float* sm) {
#pragma unroll
  for (int o = 32; o > 0; o >>= 1) v += __shfl_xor(v, o, 64);
  int w = threadIdx.x >> 6;
  __syncthreads();
  if ((threadIdx.x & 63) == 0) sm[w] = v;
  __syncthreads();
  return sm[0] + sm[1] + sm[2] + sm[3];
}

__global__ __launch_bounds__(256) void ln_phase_kernel(
    const float* __restrict__ x, const float* __restrict__ Wp,
    const float* __restrict__ gamma, const float* __restrict__ beta,
    unsigned short* __restrict__ xn, float* __restrict__ cosP,
    float* __restrict__ sinP) {
  __shared__ float sm[4];
  int row = blockIdx.x;
  int tid = threadIdx.x;
  float4 v = ((const float4*)(x + (size_t)row * D_MODEL))[tid];
  float mu = block_sum(v.x + v.y + v.z + v.w, sm) * (1.0f / D_MODEL);
  float d0 = v.x - mu, d1 = v.y - mu, d2 = v.z - mu, d3 = v.w - mu;
  float var = block_sum(d0 * d0 + d1 * d1 + d2 * d2 + d3 * d3, sm) * (1.0f / D_MODEL);
  float rinv = rsqrtf(var + 1e-5f);
  float4 g = ((const float4*)gamma)[tid];
  float4 be = ((const float4*)beta)[tid];
  float n0 = d0 * rinv * g.x + be.x;
  float n1 = d1 * rinv * g.y + be.y;
  float n2 = d2 * rinv * g.z + be.z;
  float n3 = d3 * rinv * g.w + be.w;
  ushort4 p;
  p.x = f2bf(n0); p.y = f2bf(n1); p.z = f2bf(n2); p.w = f2bf(n3);
  ((ushort4*)(xn + (size_t)row * D_MODEL))[tid] = p;
  float4 wp = ((const float4*)Wp)[tid];
  float ph = block_sum(n0 * wp.x + n1 * wp.y + n2 * wp.z + n3 * wp.w, sm);
  if (tid == 0) {
    cosP[row] = cosf(ph);
    sinP[row] = sinf(ph);
  }
}

// ---------------- kernel 3: QKV GEMM (NT, bf16 MFMA, async staging) ----------------
// z=0: Q = xn Wq^T   z=1: K = xn Wk^T   z=2: vT = Wv xn^T  (operands swapped so the
// C-fragment lane dim = token dim -> coalesced transposed store)
__global__ __launch_bounds__(256) void qkv_gemm_kernel(
    const unsigned short* __restrict__ xn, const unsigned short* __restrict__ wbf,
    unsigned short* __restrict__ q, unsigned short* __restrict__ k,
    unsigned short* __restrict__ vT) {
  __shared__ __align__(16) unsigned short As[128 * 32];
  __shared__ __align__(16) unsigned short Bs[128 * 32];
  int z = blockIdx.z;
  const unsigned short* Wm = wbf + (size_t)z * (D_MODEL * D_MODEL);
  const unsigned short* Ap = (z == 2) ? Wm : xn;
  const unsigned short* Bp = (z == 2) ? xn : Wm;
  int m0 = (z == 2) ? blockIdx.x * 128 : blockIdx.y * 128;
  int n0 = (z == 2) ? blockIdx.y * 128 : blockIdx.x * 128;
  int tid = threadIdx.x;
  int wave = tid >> 6, lane = tid & 63, quad = lane >> 4, l15 = lane & 15;
  int wm = (wave & 1) * 64, wn = (wave >> 1) * 64;
  f32x4 acc[4][4];
#pragma unroll
  for (int r = 0; r < 4; ++r)
#pragma unroll
    for (int c = 0; c < 4; ++c) acc[r][c] = (f32x4){0.f, 0.f, 0.f, 0.f};

  for (int k0 = 0; k0 < D_MODEL; k0 += 32) {
    __syncthreads();
#pragma unroll
    for (int t = 0; t < 2; ++t) {
      int c = t * 256 + tid;
      int r = c >> 2, p = c & 3;
      int qc = p ^ ((r >> 1) & 3);  // XOR swizzle: conflict-free b128 reads
      gl16(&Ap[(size_t)(m0 + r) * D_MODEL + k0 + qc * 8], &As[c * 8]);
      gl16(&Bp[(size_t)(n0 + r) * D_MODEL + k0 + qc * 8], &Bs[c * 8]);
    }
    __syncthreads();
    bf16x8 af[4], bfr[4];
#pragma unroll
    for (int r = 0; r < 4; ++r) {
      int R = wm + r * 16 + l15;
      af[r] = *(const bf16x8*)&As[R * 32 + (quad ^ ((R >> 1) & 3)) * 8];
    }
#pragma unroll
    for (int c = 0; c < 4; ++c) {
      int R = wn + c * 16 + l15;
      bfr[c] = *(const bf16x8*)&Bs[R * 32 + (quad ^ ((R >> 1) & 3)) * 8];
    }
#pragma unroll
    for (int r = 0; r < 4; ++r)
#pragma unroll
      for (int c = 0; c < 4; ++c)
        acc[r][c] = __builtin_amdgcn_mfma_f32_16x16x32_bf16(af[r], bfr[c], acc[r][c], 0, 0, 0);
  }
#pragma unroll
  for (int r = 0; r < 4; ++r) {
#pragma unroll
    for (int c = 0; c < 4; ++c) {
#pragma unroll
      for (int rr = 0; rr < 4; ++rr) {
        if (z == 2) {
          int e = m0 + wm + r * 16 + quad * 4 + rr;   // row of Wv = output channel
          int tok = n0 + wn + c * 16 + l15;           // token (lane dim -> coalesced)
          int hh = e >> 6, d = e & 63;
          int bb = tok >> 11, ss = tok & (S_LEN - 1);
          vT[(((size_t)(bb * NH + hh)) * DH + d) * S_LEN + ss] = f2bf(acc[r][c][rr]);
        } else {
          int tok = m0 + wm + r * 16 + quad * 4 + rr;
          int e = n0 + wn + c * 16 + l15;
          int hh = e >> 6, d = e & 63;
          int bb = tok >> 11, ss = tok & (S_LEN - 1);
          unsigned short val = f2bf(acc[r][c][rr] * ((z == 0) ? 0.125f : 1.0f));
          unsigned short* dst = (z == 0) ? q : k;
          dst[(((size_t)(bb * NH + hh)) * S_LEN + ss) * DH + d] = val;
        }
      }
    }
  }
}

// ---------------- kernel 4: flash attention with resonance ----------------
__global__ __launch_bounds__(256) void attn_kernel(
    const unsigned short* __restrict__ q, const unsigned short* __restrict__ kk,
    const unsigned short* __restrict__ vT, const float* __restrict__ cosP,
    const float* __restrict__ sinP, const float* __restrict__ carrier,
    const float* __restrict__ lamp, unsigned short* __restrict__ outw,
    float* __restrict__ energy) {
  __shared__ __align__(16) unsigned short Ks[64 * 64];  // XOR-swizzled chunks
  __shared__ __align__(16) unsigned short Vs[64 * 64];  // Vs[d][j], XOR-swizzled
  __shared__ __align__(16) unsigned short Ps[4][16 * 72];  // padded stride 72
  __shared__ float er[4];
  int qt = blockIdx.x, h = blockIdx.y, b = blockIdx.z;
  int bh = b * NH + h;
  int tid = threadIdx.x, wave = tid >> 6, lane = tid & 63;
  int quad = lane >> 4, l15 = lane & 15;
  float hl = 0.5f * lamp[0];
  float ch = cosf(carrier[h]), sh = sinf(carrier[h]);
  const unsigned short* qb = q + ((size_t)bh * S_LEN + qt * 64) * DH;
  const unsigned short* kb = kk + (size_t)bh * S_LEN * DH;
  const unsigned short* vb = vT + (size_t)bh * DH * S_LEN;
  const float* cpb = cosP + b * S_LEN;
  const float* spb = sinP + b * S_LEN;

  int qrow = wave * 16 + l15;
  bf16x8 aQ0 = *(const bf16x8*)(qb + qrow * DH + quad * 8);
  bf16x8 aQ1 = *(const bf16x8*)(qb + qrow * DH + 32 + quad * 8);

  float cI[4], sI[4], m_i[4], l_i[4];
  f32x4 o[4];
#pragma unroll
  for (int r = 0; r < 4; ++r) {
    int il = qt * 64 + wave * 16 + quad * 4 + r;
    cI[r] = hl * cpb[il];
    sI[r] = hl * spb[il];
    m_i[r] = -3.0e38f;
    l_i[r] = 0.f;
    o[r] = (f32x4){0.f, 0.f, 0.f, 0.f};
  }

  for (int j0 = 0; j0 < S_LEN; j0 += 64) {
    __syncthreads();
#pragma unroll
    for (int t = 0; t < 2; ++t) {
      int c = t * 256 + tid;
      int r = c >> 3, p = c & 7;
      int qc = p ^ (r & 7);  // XOR swizzle
      gl16(&kb[(size_t)(j0 + r) * DH + qc * 8], &Ks[c * 8]);
      gl16(&vb[(size_t)r * S_LEN + j0 + qc * 8], &Vs[c * 8]);
    }
    __syncthreads();

    float Sc[4][4];
#pragma unroll
    for (int cg = 0; cg < 4; ++cg) {
      int row = cg * 16 + l15, g = row & 7;
      bf16x8 b0 = *(const bf16x8*)&Ks[row * 64 + (quad ^ g) * 8];
      bf16x8 b1 = *(const bf16x8*)&Ks[row * 64 + ((quad + 4) ^ g) * 8];
      f32x4 cfr = (f32x4){0.f, 0.f, 0.f, 0.f};
      cfr = __builtin_amdgcn_mfma_f32_16x16x32_bf16(aQ0, b0, cfr, 0, 0, 0);
      cfr = __builtin_amdgcn_mfma_f32_16x16x32_bf16(aQ1, b1, cfr, 0, 0, 0);
      int j = j0 + cg * 16 + l15;
      float cj = cpb[j], sj = spb[j];
#pragma unroll
      for (int r = 0; r < 4; ++r) Sc[cg][r] = cfr[r] + cI[r] * cj + sI[r] * sj;
    }
#pragma unroll
    for (int r = 0; r < 4; ++r) {
      float mx = fmaxf(fmaxf(Sc[0][r], Sc[1][r]), fmaxf(Sc[2][r], Sc[3][r]));
      mx = fmaxf(mx, __shfl_xor(mx, 1, 64));
      mx = fmaxf(mx, __shfl_xor(mx, 2, 64));
      mx = fmaxf(mx, __shfl_xor(mx, 4, 64));
      mx = fmaxf(mx, __shfl_xor(mx, 8, 64));
      float mnew = fmaxf(m_i[r], mx);
      float ps = 0.f;
#pragma unroll
      for (int cg = 0; cg < 4; ++cg) {
        float pv = __expf(Sc[cg][r] - mnew);
        Sc[cg][r] = pv;
        ps += pv;
      }
      ps += __shfl_xor(ps, 1, 64);
      ps += __shfl_xor(ps, 2, 64);
      ps += __shfl_xor(ps, 4, 64);
      ps += __shfl_xor(ps, 8, 64);
      float alpha = __expf(m_i[r] - mnew);
      l_i[r] = l_i[r] * alpha + ps;
      m_i[r] = mnew;
#pragma unroll
      for (int dg = 0; dg < 4; ++dg) o[dg][r] *= alpha;
    }
    // P (C-layout) -> A-layout via per-wave LDS round trip (padded rows)
#pragma unroll
    for (int cg = 0; cg < 4; ++cg)
#pragma unroll
      for (int r = 0; r < 4; ++r)
        Ps[wave][(quad * 4 + r) * 72 + cg * 16 + l15] = f2bf(Sc[cg][r]);
#pragma unroll
    for (int hh2 = 0; hh2 < 2; ++hh2) {
      bf16x8 aP = *(const bf16x8*)&Ps[wave][l15 * 72 + hh2 * 32 + quad * 8];
#pragma unroll
      for (int dg = 0; dg < 4; ++dg) {
        int vrow = dg * 16 + l15, gv = vrow & 7;
        bf16x8 bV = *(const bf16x8*)&Vs[vrow * 64 + ((hh2 * 4 + quad) ^ gv) * 8];
        o[dg] = __builtin_amdgcn_mfma_f32_16x16x32_bf16(aP, bV, o[dg], 0, 0, 0);
      }
    }
  }
  // epilogue: normalize, gate, store, energy
  float esum = 0.f;
#pragma unroll
  for (int r = 0; r < 4; ++r) {
    int il = wave * 16 + quad * 4 + r;
    int srow = qt * 64 + il;
    float cp = cpb[srow], sp = spb[srow];
    float gate = 0.5f + 0.5f * (cp * ch + sp * sh);
    float gl = gate / l_i[r];
    int tok = b * S_LEN + srow;
#pragma unroll
    for (int dg = 0; dg < 4; ++dg) {
      float val = o[dg][r] * gl;
      esum += fabsf(val);
      outw[(size_t)tok * D_MODEL + h * DH + dg * 16 + l15] = f2bf(val);
    }
  }
#pragma unroll
  for (int off = 32; off > 0; off >>= 1) esum += __shfl_xor(esum, off, 64);
  if (lane == 0) er[wave] = esum;
  __syncthreads();
  if (tid == 0) atomicAdd(energy, er[0] + er[1] + er[2] + er[3]);
}

// ---------------- kernel 5: output projection + residual ----------------
__global__ __launch_bounds__(256) void out_gemm_kernel(
    const unsigned short* __restrict__ A, const unsigned short* __restrict__ Wo,
    const float* __restrict__ x, float* __restrict__ y) {
  __shared__ __align__(16) unsigned short As[128 * 32];
  __shared__ __align__(16) unsigned short Bs[128 * 32];
  int tid = threadIdx.x;
  int wave = tid >> 6, lane = tid & 63, quad = lane >> 4, l15 = lane & 15;
  int wm = (wave & 1) * 64, wn = (wave >> 1) * 64;
  int m0 = blockIdx.y * 128, n0 = blockIdx.x * 128;
  f32x4 acc[4][4];
#pragma unroll
  for (int r = 0; r < 4; ++r)
#pragma unroll
    for (int c = 0; c < 4; ++c) acc[r][c] = (f32x4){0.f, 0.f, 0.f, 0.f};

  for (int k0 = 0; k0 < D_MODEL; k0 += 32) {
    __syncthreads();
#pragma unroll
    for (int t = 0; t < 2; ++t) {
      int c = t * 256 + tid;
      int r = c >> 2, p = c & 3;
      int qc = p ^ ((r >> 1) & 3);
      gl16(&A[(size_t)(m0 + r) * D_MODEL + k0 + qc * 8], &As[c * 8]);
      gl16(&Wo[(size_t)(n0 + r) * D_MODEL + k0 + qc * 8], &Bs[c * 8]);
    }
    __syncthreads();
    bf16x8 af[4], bfr[4];
#pragma unroll
    for (int r = 0; r < 4; ++r) {
      int R = wm + r * 16 + l15;
      af[r] = *(const bf16x8*)&As[R * 32 + (quad ^ ((R >> 1) & 3)) * 8];
    }
#pragma unroll
    for (int c = 0; c < 4; ++c) {
      int R = wn + c * 16 + l15;
      bfr[c] = *(const bf16x8*)&Bs[R * 32 + (quad ^ ((R >> 1) & 3)) * 8];
    }
#pragma unroll
    for (int r = 0; r < 4; ++r)
#pragma unroll
      for (int c = 0; c < 4; ++c)
        acc[r][c] = __builtin_amdgcn_mfma_f32_16x16x32_bf16(af[r], bfr[c], acc[r][c], 0, 0, 0);
  }
#pragma unroll
  for (int r = 0; r < 4; ++r) {
#pragma unroll
    for (int c = 0; c < 4; ++c) {
      int dcol = n0 + wn + c * 16 + l15;
#pragma unroll
      for (int rr = 0; rr < 4; ++rr) {
        int tok = m0 + wm + r * 16 + quad * 4 + rr;
        size_t idx = (size_t)tok * D_MODEL + dcol;
        y[idx] = x[idx] + acc[r][c][rr];
      }
    }
  }
}

extern "C" void kernel_launch(void* const* d_in, const int* in_sizes, int n_in,
                              void* d_out, int out_size, void* d_ws, size_t ws_size,
                              hipStream_t stream) {
  const float* x = (const float*)d_in[0];
  const float* Wq = (const float*)d_in[1];
  const float* Wk = (const float*)d_in[2];
  const float* Wv = (const float*)d_in[3];
  const float* Wo = (const float*)d_in[4];
  const float* Wp = (const float*)d_in[5];
  const float* gamma = (const float*)d_in[6];
  const float* beta = (const float*)d_in[7];
  const float* carrier = (const float*)d_in[8];
  const float* lam = (const float*)d_in[9];

  char* ws = (char*)d_ws;
  const size_t MB = 1024 * 1024;
  unsigned short* wbf = (unsigned short*)(ws);             // 8 MB: Wq|Wk|Wv|Wo bf16
  unsigned short* xn = (unsigned short*)(ws + 8 * MB);     // 8 MB
  unsigned short* qq = (unsigned short*)(ws + 16 * MB);    // 8 MB (B,H,S,dh)
  unsigned short* kk = (unsigned short*)(ws + 24 * MB);    // 8 MB (B,H,S,dh)
  unsigned short* vT = (unsigned short*)(ws + 32 * MB);    // 8 MB (B,H,dh,S)
  unsigned short* outw = (unsigned short*)(ws + 40 * MB);  // 8 MB (tok, e)
  float* cosP = (float*)(ws + 48 * MB);                    // 16 KB
  float* sinP = (float*)(ws + 48 * MB + 16 * 1024);        // 16 KB

  float* y = (float*)d_out;
  float* energy = y + (out_size - 1);

  prep_kernel<<<4096, 256, 0, stream>>>(Wq, Wk, Wv, Wo, wbf, energy);
  ln_phase_kernel<<<M_TOK, 256, 0, stream>>>(x, Wp, gamma, beta, xn, cosP, sinP);
  qkv_gemm_kernel<<<dim3(8, 32, 3), 256, 0, stream>>>(xn, wbf, qq, kk, vT);
  attn_kernel<<<dim3(32, 16, 2), 256, 0, stream>>>(qq, kk, vT, cosP, sinP, carrier,
                                                   lam, outw, energy);
  out_gemm_kernel<<<dim3(8, 32), 256, 0, stream>>>(outw, wbf + 3 * D_MODEL * D_MODEL,
                                                   x, y);
}